// Round 6
// baseline (1054.680 us; speedup 1.0000x reference)
//
#include <hip/hip_runtime.h>

#define NCH    8
#define NBASIS 30
#define NXS    256
#define NF     200
#define NX     (NXS*NXS*2)      // 131072
#define NIMG   (NCH*NBASIS)     // 240

typedef float f32x2 __attribute__((ext_vector_type(2)));

__device__ __forceinline__ int bitrev8(int v) {
    return (int)(__builtin_bitreverse32((unsigned)v) >> 24);
}

// ---------------------------------------------------------------------------
// Pass 1: w = (x * csm) * (-1)^(row+col); FFT along the contiguous (col) axis.
// ---------------------------------------------------------------------------
__global__ __launch_bounds__(256) void fft_rows_kernel(
        const float* __restrict__ x, const float* __restrict__ csm,
        float* __restrict__ A) {
    __shared__ float ldsRe[4][256];
    __shared__ float ldsIm[4][256];
    __shared__ float twRe[128], twIm[128];

    const int tid   = threadIdx.x;
    const int slice = tid >> 6;
    const int lane  = tid & 63;
    const int blk   = blockIdx.x;       // m*64 + rowTile
    const int m     = blk >> 6;
    const int row   = ((blk & 63) << 2) + slice;
    const int c     = m / NBASIS;
    const int b     = m - c * NBASIS;

    if (tid < 128) {
        float a = (float)tid * (1.0f / 128.0f);   // theta = pi * a
        twRe[tid] =  cospif(a);
        twIm[tid] = -sinpif(a);
    }

    const float* xr = x   + ((size_t)(b * NXS + row) * NXS) * 2;
    const float* cr = csm + ((size_t)(c * NXS + row) * NXS) * 2;
    #pragma unroll
    for (int j = 0; j < 4; ++j) {
        int col = lane + 64 * j;
        float2 xv = *(const float2*)(xr + col * 2);
        float2 cv = *(const float2*)(cr + col * 2);
        float s = ((row + col) & 1) ? -1.0f : 1.0f;
        ldsRe[slice][col] = s * (xv.x * cv.x - xv.y * cv.y);
        ldsIm[slice][col] = s * (xv.x * cv.y + xv.y * cv.x);
    }
    __syncthreads();

    #pragma unroll
    for (int half = 128; half >= 1; half >>= 1) {
        #pragma unroll
        for (int qq = 0; qq < 2; ++qq) {
            int q  = lane + 64 * qq;
            int g  = q / half;
            int j  = q - g * half;
            int i0 = g * 2 * half + j;
            int i1 = i0 + half;
            float ar = ldsRe[slice][i0], ai = ldsIm[slice][i0];
            float br = ldsRe[slice][i1], bi = ldsIm[slice][i1];
            ldsRe[slice][i0] = ar + br;
            ldsIm[slice][i0] = ai + bi;
            float dr = ar - br, di = ai - bi;
            int k = j * (128 / half);
            float wr = twRe[k], wi = twIm[k];
            ldsRe[slice][i1] = dr * wr - di * wi;
            ldsIm[slice][i1] = dr * wi + di * wr;
        }
        __syncthreads();
    }

    float* outp = A + (size_t)m * (NXS * NXS * 2) + (size_t)row * NXS * 2;
    #pragma unroll
    for (int j = 0; j < 4; ++j) {
        int k  = lane + 64 * j;
        int rk = bitrev8(k);
        *(float2*)(outp + k * 2) = make_float2(ldsRe[slice][rk], ldsIm[slice][rk]);
    }
}

// ---------------------------------------------------------------------------
// Pass 2: FFT along the row axis (stride-256 columns), in place.
// ---------------------------------------------------------------------------
#define CTILE 16
__global__ __launch_bounds__(256) void fft_cols_kernel(float* __restrict__ A) {
    __shared__ float ldsRe[CTILE][257];
    __shared__ float ldsIm[CTILE][257];
    __shared__ float twRe[128], twIm[128];

    const int tid = threadIdx.x;
    const int blk = blockIdx.x;
    const int m   = blk >> 4;             // 16 tiles per image
    const int k0  = (blk & 15) * CTILE;

    if (tid < 128) {
        float a = (float)tid * (1.0f / 128.0f);
        twRe[tid] =  cospif(a);
        twIm[tid] = -sinpif(a);
    }

    float* base = A + (size_t)m * (NXS * NXS * 2);
    #pragma unroll
    for (int it = 0; it < 16; ++it) {
        int li = it * 256 + tid;
        int r  = li >> 4;
        int cc = li & 15;
        float2 v = *(const float2*)(base + ((size_t)r * NXS + k0 + cc) * 2);
        ldsRe[cc][r] = v.x;
        ldsIm[cc][r] = v.y;
    }
    __syncthreads();

    const int slice = tid >> 6;
    const int lane  = tid & 63;

    #pragma unroll
    for (int half = 128; half >= 1; half >>= 1) {
        #pragma unroll
        for (int ci = 0; ci < 4; ++ci) {
            int col = slice * 4 + ci;
            #pragma unroll
            for (int qq = 0; qq < 2; ++qq) {
                int q  = lane + 64 * qq;
                int g  = q / half;
                int j  = q - g * half;
                int i0 = g * 2 * half + j;
                int i1 = i0 + half;
                float ar = ldsRe[col][i0], ai = ldsIm[col][i0];
                float br = ldsRe[col][i1], bi = ldsIm[col][i1];
                ldsRe[col][i0] = ar + br;
                ldsIm[col][i0] = ai + bi;
                float dr = ar - br, di = ai - bi;
                int k = j * (128 / half);
                float wr = twRe[k], wi = twIm[k];
                ldsRe[col][i1] = dr * wr - di * wi;
                ldsIm[col][i1] = dr * wi + di * wr;
            }
        }
        __syncthreads();
    }

    #pragma unroll
    for (int it = 0; it < 16; ++it) {
        int li = it * 256 + tid;
        int ky = li >> 4;
        int cc = li & 15;
        int kx = k0 + cc;
        int rk = bitrev8(ky);
        float s = (((ky + kx) & 1) ? -1.0f : 1.0f) * (1.0f / 256.0f);
        *(float2*)(base + ((size_t)ky * NXS + kx) * 2) =
            make_float2(s * ldsRe[cc][rk], s * ldsIm[cc][rk]);
    }
}

// ---------------------------------------------------------------------------
// Stage 3: out[c,f,n] = mask[f,n] * sum_b Y[c,b,n] * VT[b,f]
// R5 post-mortem: allocator spills a pinned 60-VGPR yr[] at any attainable
// occupancy target (R3: 40 VGPR, R5: 52 VGPR w/ waves_per_eu(2,4)) -> stop
// fighting regalloc. Stage Y through LDS instead: block = 512 n x 1 channel,
// Y tile (30 x 512 f32 = 60 KB) staged coalesced once (each Y element fetched
// from HBM exactly once chip-wide), f-loop re-reads it via ds_read_b64
// (2-way bank aliasing = free). Per-thread live set ~40 regs -> no spills.
// ---------------------------------------------------------------------------
#define FT 8
__global__ __launch_bounds__(256) void project_mask_kernel(
        const float* __restrict__ Y, const float* __restrict__ VT,
        const void* __restrict__ maskT, float* __restrict__ out) {
    __shared__ f32x2 ylds[NBASIS][256];     // 61,440 B

    const int tid = threadIdx.x;
    const int c   = blockIdx.y;
    const int n0  = blockIdx.x * 512;       // tile base (in n units)
    const int n   = n0 + tid * 2;           // this thread's pair

    // Stage Y tile: 30 rows x 256 f32x2, coalesced (512 B / wave / row).
    const f32x2* Yp = (const f32x2*)(Y + (size_t)c * NBASIS * NX + n0);
    #pragma unroll
    for (int b = 0; b < NBASIS; ++b)
        ylds[b][tid] = Yp[(size_t)b * (NX / 2) + tid];

    // Detect mask storage: bool-as-byte vs int32 (uniform, scalar loads).
    const unsigned* mw = (const unsigned*)maskT;
    bool byteMode = false;
    #pragma unroll
    for (int i = 0; i < 32; ++i) byteMode |= (mw[i] > 1u);

    __syncthreads();

    const unsigned char* m8  = (const unsigned char*)maskT;
    const int*           m32 = (const int*)maskT;

    #pragma unroll 1
    for (int f0 = 0; f0 < NF; f0 += FT) {
        f32x2 acc[FT];
        #pragma unroll
        for (int j = 0; j < FT; ++j) acc[j] = (f32x2)(0.0f, 0.0f);

        #pragma unroll
        for (int b = 0; b < NBASIS; ++b) {
            f32x2 y = ylds[b][tid];
            #pragma unroll
            for (int j = 0; j < FT; ++j) {
                float vt = VT[b * NF + f0 + j];      // uniform -> SGPR
                acc[j].x = fmaf(y.x, vt, acc[j].x);
                acc[j].y = fmaf(y.y, vt, acc[j].y);
            }
        }

        #pragma unroll
        for (int j = 0; j < FT; ++j) {
            int f = f0 + j;
            bool m0, m1;
            if (byteMode) {
                unsigned short mv = *(const unsigned short*)(m8 + (size_t)f * NX + n);
                m0 = (mv & 0xFF) != 0;
                m1 = (mv >> 8)   != 0;
            } else {
                const int* mp = m32 + (size_t)f * NX + n;
                m0 = mp[0] != 0;
                m1 = mp[1] != 0;
            }
            f32x2 o;
            o.x = m0 ? acc[j].x : 0.0f;
            o.y = m1 ? acc[j].y : 0.0f;
            __builtin_nontemporal_store(o,
                (f32x2*)(out + ((size_t)(c * NF + f)) * NX + n));
        }
    }
}

extern "C" void kernel_launch(void* const* d_in, const int* in_sizes, int n_in,
                              void* d_out, int out_size, void* d_ws, size_t ws_size,
                              hipStream_t stream) {
    const float* x    = (const float*)d_in[0];   // (30,256,256,2) f32
    const float* csm  = (const float*)d_in[1];   // (8,256,256,2) f32
    const float* VT   = (const float*)d_in[2];   // (30,200) f32
    const void*  mask = d_in[3];                 // (200,131072) bool/int
    float* out = (float*)d_out;                  // (8,200,131072) f32
    float* A   = (float*)d_ws;                   // 240*256*256*2 f32 = 125.8 MB

    fft_rows_kernel<<<NIMG * 64, 256, 0, stream>>>(x, csm, A);
    fft_cols_kernel<<<NIMG * 16, 256, 0, stream>>>(A);
    project_mask_kernel<<<dim3(NX / 512, NCH), 256, 0, stream>>>(A, VT, mask, out);
}

// Round 7
// 607.328 us; speedup vs baseline: 1.7366x; 1.7366x over previous
//
#include <hip/hip_runtime.h>

#define NCH    8
#define NBASIS 30
#define NXS    256
#define NF     200
#define NX     (NXS*NXS*2)      // 131072
#define NIMG   (NCH*NBASIS)     // 240

typedef float f32x2 __attribute__((ext_vector_type(2)));

__device__ __forceinline__ int bitrev8(int v) {
    return (int)(__builtin_bitreverse32((unsigned)v) >> 24);
}

// ---------------------------------------------------------------------------
// Pass 1: w = (x * csm) * (-1)^(row+col); FFT along the contiguous (col) axis.
// ---------------------------------------------------------------------------
__global__ __launch_bounds__(256) void fft_rows_kernel(
        const float* __restrict__ x, const float* __restrict__ csm,
        float* __restrict__ A) {
    __shared__ float ldsRe[4][256];
    __shared__ float ldsIm[4][256];
    __shared__ float twRe[128], twIm[128];

    const int tid   = threadIdx.x;
    const int slice = tid >> 6;
    const int lane  = tid & 63;
    const int blk   = blockIdx.x;       // m*64 + rowTile
    const int m     = blk >> 6;
    const int row   = ((blk & 63) << 2) + slice;
    const int c     = m / NBASIS;
    const int b     = m - c * NBASIS;

    if (tid < 128) {
        float a = (float)tid * (1.0f / 128.0f);   // theta = pi * a
        twRe[tid] =  cospif(a);
        twIm[tid] = -sinpif(a);
    }

    const float* xr = x   + ((size_t)(b * NXS + row) * NXS) * 2;
    const float* cr = csm + ((size_t)(c * NXS + row) * NXS) * 2;
    #pragma unroll
    for (int j = 0; j < 4; ++j) {
        int col = lane + 64 * j;
        float2 xv = *(const float2*)(xr + col * 2);
        float2 cv = *(const float2*)(cr + col * 2);
        float s = ((row + col) & 1) ? -1.0f : 1.0f;
        ldsRe[slice][col] = s * (xv.x * cv.x - xv.y * cv.y);
        ldsIm[slice][col] = s * (xv.x * cv.y + xv.y * cv.x);
    }
    __syncthreads();

    #pragma unroll
    for (int half = 128; half >= 1; half >>= 1) {
        #pragma unroll
        for (int qq = 0; qq < 2; ++qq) {
            int q  = lane + 64 * qq;
            int g  = q / half;
            int j  = q - g * half;
            int i0 = g * 2 * half + j;
            int i1 = i0 + half;
            float ar = ldsRe[slice][i0], ai = ldsIm[slice][i0];
            float br = ldsRe[slice][i1], bi = ldsIm[slice][i1];
            ldsRe[slice][i0] = ar + br;
            ldsIm[slice][i0] = ai + bi;
            float dr = ar - br, di = ai - bi;
            int k = j * (128 / half);
            float wr = twRe[k], wi = twIm[k];
            ldsRe[slice][i1] = dr * wr - di * wi;
            ldsIm[slice][i1] = dr * wi + di * wr;
        }
        __syncthreads();
    }

    float* outp = A + (size_t)m * (NXS * NXS * 2) + (size_t)row * NXS * 2;
    #pragma unroll
    for (int j = 0; j < 4; ++j) {
        int k  = lane + 64 * j;
        int rk = bitrev8(k);
        *(float2*)(outp + k * 2) = make_float2(ldsRe[slice][rk], ldsIm[slice][rk]);
    }
}

// ---------------------------------------------------------------------------
// Pass 2: FFT along the row axis (stride-256 columns), in place.
// ---------------------------------------------------------------------------
#define CTILE 16
__global__ __launch_bounds__(256) void fft_cols_kernel(float* __restrict__ A) {
    __shared__ float ldsRe[CTILE][257];
    __shared__ float ldsIm[CTILE][257];
    __shared__ float twRe[128], twIm[128];

    const int tid = threadIdx.x;
    const int blk = blockIdx.x;
    const int m   = blk >> 4;             // 16 tiles per image
    const int k0  = (blk & 15) * CTILE;

    if (tid < 128) {
        float a = (float)tid * (1.0f / 128.0f);
        twRe[tid] =  cospif(a);
        twIm[tid] = -sinpif(a);
    }

    float* base = A + (size_t)m * (NXS * NXS * 2);
    #pragma unroll
    for (int it = 0; it < 16; ++it) {
        int li = it * 256 + tid;
        int r  = li >> 4;
        int cc = li & 15;
        float2 v = *(const float2*)(base + ((size_t)r * NXS + k0 + cc) * 2);
        ldsRe[cc][r] = v.x;
        ldsIm[cc][r] = v.y;
    }
    __syncthreads();

    const int slice = tid >> 6;
    const int lane  = tid & 63;

    #pragma unroll
    for (int half = 128; half >= 1; half >>= 1) {
        #pragma unroll
        for (int ci = 0; ci < 4; ++ci) {
            int col = slice * 4 + ci;
            #pragma unroll
            for (int qq = 0; qq < 2; ++qq) {
                int q  = lane + 64 * qq;
                int g  = q / half;
                int j  = q - g * half;
                int i0 = g * 2 * half + j;
                int i1 = i0 + half;
                float ar = ldsRe[col][i0], ai = ldsIm[col][i0];
                float br = ldsRe[col][i1], bi = ldsIm[col][i1];
                ldsRe[col][i0] = ar + br;
                ldsIm[col][i0] = ai + bi;
                float dr = ar - br, di = ai - bi;
                int k = j * (128 / half);
                float wr = twRe[k], wi = twIm[k];
                ldsRe[col][i1] = dr * wr - di * wi;
                ldsIm[col][i1] = dr * wi + di * wr;
            }
        }
        __syncthreads();
    }

    #pragma unroll
    for (int it = 0; it < 16; ++it) {
        int li = it * 256 + tid;
        int ky = li >> 4;
        int cc = li & 15;
        int kx = k0 + cc;
        int rk = bitrev8(ky);
        float s = (((ky + kx) & 1) ? -1.0f : 1.0f) * (1.0f / 256.0f);
        *(float2*)(base + ((size_t)ky * NXS + kx) * 2) =
            make_float2(s * ldsRe[cc][rk], s * ldsIm[cc][rk]);
    }
}

// ---------------------------------------------------------------------------
// Stage 3: out[c,f,n] = mask[f,n] * sum_b Y[c,b,n] * VT[b,f]
// R6 post-mortem: 60 KB LDS tile -> 2 blocks/CU -> 23% occupancy ->
// latency-bound (1005 us). This version: 1 n/thread, 256-n tile -> 30 KB LDS
// -> 5 blocks/CU (~62% occupancy), per-thread live set ~40 regs (acc[8] f32 +
// 8 mask words) so regalloc needs no coaxing. Mask loads issue at the top of
// each f0 iter; their values are consumed only AFTER the 240-FMA block, so
// the vmcnt wait sits ~480 issue-cycles after issue (latency hidden).
// ---------------------------------------------------------------------------
#define FT 8
__global__ __launch_bounds__(256) void project_mask_kernel(
        const float* __restrict__ Y, const float* __restrict__ VT,
        const void* __restrict__ maskT, float* __restrict__ out) {
    __shared__ float ylds[NBASIS][256];     // 30,720 B

    const int tid = threadIdx.x;
    const int c   = blockIdx.y;
    const int n0  = blockIdx.x * 256;
    const int n   = n0 + tid;

    // Stage Y tile: 30 rows x 256 f32, coalesced 1 KB rows; each Y element
    // is fetched from HBM exactly once chip-wide.
    const float* Yp = Y + (size_t)c * NBASIS * NX + n0;
    #pragma unroll
    for (int b = 0; b < NBASIS; ++b)
        ylds[b][tid] = Yp[(size_t)b * NX + tid];

    // Detect mask storage: bool-as-byte vs int32 (uniform, scalar loads).
    const unsigned* mw = (const unsigned*)maskT;
    bool byteMode = false;
    #pragma unroll
    for (int i = 0; i < 32; ++i) byteMode |= (mw[i] > 1u);

    __syncthreads();

    const unsigned char* m8  = (const unsigned char*)maskT;
    const int*           m32 = (const int*)maskT;

    #pragma unroll 1
    for (int f0 = 0; f0 < NF; f0 += FT) {
        // Issue mask loads first; raw values consumed only after the FMAs.
        unsigned mvb[FT];
        #pragma unroll
        for (int j = 0; j < FT; ++j) {
            size_t off = (size_t)(f0 + j) * NX + n;
            mvb[j] = byteMode ? (unsigned)m8[off] : (unsigned)m32[off];
        }

        float acc[FT];
        #pragma unroll
        for (int j = 0; j < FT; ++j) acc[j] = 0.0f;

        #pragma unroll
        for (int b = 0; b < NBASIS; ++b) {
            float y = ylds[b][tid];
            #pragma unroll
            for (int j = 0; j < FT; ++j)
                acc[j] = fmaf(y, VT[b * NF + f0 + j], acc[j]);  // vt uniform -> SGPR
        }

        #pragma unroll
        for (int j = 0; j < FT; ++j) {
            float o = (mvb[j] != 0u) ? acc[j] : 0.0f;
            __builtin_nontemporal_store(o,
                out + ((size_t)(c * NF + f0 + j)) * NX + n);
        }
    }
}

extern "C" void kernel_launch(void* const* d_in, const int* in_sizes, int n_in,
                              void* d_out, int out_size, void* d_ws, size_t ws_size,
                              hipStream_t stream) {
    const float* x    = (const float*)d_in[0];   // (30,256,256,2) f32
    const float* csm  = (const float*)d_in[1];   // (8,256,256,2) f32
    const float* VT   = (const float*)d_in[2];   // (30,200) f32
    const void*  mask = d_in[3];                 // (200,131072) bool/int
    float* out = (float*)d_out;                  // (8,200,131072) f32
    float* A   = (float*)d_ws;                   // 240*256*256*2 f32 = 125.8 MB

    fft_rows_kernel<<<NIMG * 64, 256, 0, stream>>>(x, csm, A);
    fft_cols_kernel<<<NIMG * 16, 256, 0, stream>>>(A);
    project_mask_kernel<<<dim3(NX / 256, NCH), 256, 0, stream>>>(A, VT, mask, out);
}

// Round 8
// 459.504 us; speedup vs baseline: 2.2953x; 1.3217x over previous
//
#include <hip/hip_runtime.h>

#define NCH    8
#define NBASIS 30
#define NXS    256
#define NF     200
#define NX     (NXS*NXS*2)      // 131072
#define NIMG   (NCH*NBASIS)     // 240

typedef float f32x2 __attribute__((ext_vector_type(2)));

__device__ __forceinline__ int bitrev8(int v) {
    return (int)(__builtin_bitreverse32((unsigned)v) >> 24);
}

// ---------------------------------------------------------------------------
// Pass 1: w = (x * csm) * (-1)^(row+col); FFT along the contiguous (col) axis.
// ---------------------------------------------------------------------------
__global__ __launch_bounds__(256) void fft_rows_kernel(
        const float* __restrict__ x, const float* __restrict__ csm,
        float* __restrict__ A) {
    __shared__ float ldsRe[4][256];
    __shared__ float ldsIm[4][256];
    __shared__ float twRe[128], twIm[128];

    const int tid   = threadIdx.x;
    const int slice = tid >> 6;
    const int lane  = tid & 63;
    const int blk   = blockIdx.x;       // m*64 + rowTile
    const int m     = blk >> 6;
    const int row   = ((blk & 63) << 2) + slice;
    const int c     = m / NBASIS;
    const int b     = m - c * NBASIS;

    if (tid < 128) {
        float a = (float)tid * (1.0f / 128.0f);   // theta = pi * a
        twRe[tid] =  cospif(a);
        twIm[tid] = -sinpif(a);
    }

    const float* xr = x   + ((size_t)(b * NXS + row) * NXS) * 2;
    const float* cr = csm + ((size_t)(c * NXS + row) * NXS) * 2;
    #pragma unroll
    for (int j = 0; j < 4; ++j) {
        int col = lane + 64 * j;
        float2 xv = *(const float2*)(xr + col * 2);
        float2 cv = *(const float2*)(cr + col * 2);
        float s = ((row + col) & 1) ? -1.0f : 1.0f;
        ldsRe[slice][col] = s * (xv.x * cv.x - xv.y * cv.y);
        ldsIm[slice][col] = s * (xv.x * cv.y + xv.y * cv.x);
    }
    __syncthreads();

    #pragma unroll
    for (int half = 128; half >= 1; half >>= 1) {
        #pragma unroll
        for (int qq = 0; qq < 2; ++qq) {
            int q  = lane + 64 * qq;
            int g  = q / half;
            int j  = q - g * half;
            int i0 = g * 2 * half + j;
            int i1 = i0 + half;
            float ar = ldsRe[slice][i0], ai = ldsIm[slice][i0];
            float br = ldsRe[slice][i1], bi = ldsIm[slice][i1];
            ldsRe[slice][i0] = ar + br;
            ldsIm[slice][i0] = ai + bi;
            float dr = ar - br, di = ai - bi;
            int k = j * (128 / half);
            float wr = twRe[k], wi = twIm[k];
            ldsRe[slice][i1] = dr * wr - di * wi;
            ldsIm[slice][i1] = dr * wi + di * wr;
        }
        __syncthreads();
    }

    float* outp = A + (size_t)m * (NXS * NXS * 2) + (size_t)row * NXS * 2;
    #pragma unroll
    for (int j = 0; j < 4; ++j) {
        int k  = lane + 64 * j;
        int rk = bitrev8(k);
        *(float2*)(outp + k * 2) = make_float2(ldsRe[slice][rk], ldsIm[slice][rk]);
    }
}

// ---------------------------------------------------------------------------
// Pass 2: FFT along the row axis (stride-256 columns), in place.
// ---------------------------------------------------------------------------
#define CTILE 16
__global__ __launch_bounds__(256) void fft_cols_kernel(float* __restrict__ A) {
    __shared__ float ldsRe[CTILE][257];
    __shared__ float ldsIm[CTILE][257];
    __shared__ float twRe[128], twIm[128];

    const int tid = threadIdx.x;
    const int blk = blockIdx.x;
    const int m   = blk >> 4;             // 16 tiles per image
    const int k0  = (blk & 15) * CTILE;

    if (tid < 128) {
        float a = (float)tid * (1.0f / 128.0f);
        twRe[tid] =  cospif(a);
        twIm[tid] = -sinpif(a);
    }

    float* base = A + (size_t)m * (NXS * NXS * 2);
    #pragma unroll
    for (int it = 0; it < 16; ++it) {
        int li = it * 256 + tid;
        int r  = li >> 4;
        int cc = li & 15;
        float2 v = *(const float2*)(base + ((size_t)r * NXS + k0 + cc) * 2);
        ldsRe[cc][r] = v.x;
        ldsIm[cc][r] = v.y;
    }
    __syncthreads();

    const int slice = tid >> 6;
    const int lane  = tid & 63;

    #pragma unroll
    for (int half = 128; half >= 1; half >>= 1) {
        #pragma unroll
        for (int ci = 0; ci < 4; ++ci) {
            int col = slice * 4 + ci;
            #pragma unroll
            for (int qq = 0; qq < 2; ++qq) {
                int q  = lane + 64 * qq;
                int g  = q / half;
                int j  = q - g * half;
                int i0 = g * 2 * half + j;
                int i1 = i0 + half;
                float ar = ldsRe[col][i0], ai = ldsIm[col][i0];
                float br = ldsRe[col][i1], bi = ldsIm[col][i1];
                ldsRe[col][i0] = ar + br;
                ldsIm[col][i0] = ai + bi;
                float dr = ar - br, di = ai - bi;
                int k = j * (128 / half);
                float wr = twRe[k], wi = twIm[k];
                ldsRe[col][i1] = dr * wr - di * wi;
                ldsIm[col][i1] = dr * wi + di * wr;
            }
        }
        __syncthreads();
    }

    #pragma unroll
    for (int it = 0; it < 16; ++it) {
        int li = it * 256 + tid;
        int ky = li >> 4;
        int cc = li & 15;
        int kx = k0 + cc;
        int rk = bitrev8(ky);
        float s = (((ky + kx) & 1) ? -1.0f : 1.0f) * (1.0f / 256.0f);
        *(float2*)(base + ((size_t)ky * NXS + kx) * 2) =
            make_float2(s * ldsRe[cc][rk], s * ldsIm[cc][rk]);
    }
}

// ---------------------------------------------------------------------------
// Stage 3: out[c,f,n] = mask[f,n] * sum_b Y[c,b,n] * VT[b,f]
// R7 post-mortem: LDS version latency-stalled (VALU 35%, HBM 2 TB/s, occ 49%)
// on mixed DS+SMEM lgkmcnt drains. This version: NO LDS, FT=4, 1 n/thread ->
// live set yr[30]+acc[4]+mask[4+4]+addr ~48 VGPR, which FITS the allocator's
// default 64-VGPR/8-wave budget (R0/R3/R5 spilled because their live sets
// were 90+). Full occupancy + register-resident y; mask loads software-
// pipelined one f0-iteration ahead.
// ---------------------------------------------------------------------------
#define FT 4
__global__ __launch_bounds__(256) void project_mask_kernel(
        const float* __restrict__ Y, const float* __restrict__ VT,
        const void* __restrict__ maskT, float* __restrict__ out) {
    const int n = blockIdx.x * 256 + threadIdx.x;
    const int c = blockIdx.y;

    // Detect mask storage: bool-as-byte vs int32 (uniform, scalar loads).
    const unsigned* mw = (const unsigned*)maskT;
    bool byteMode = false;
    #pragma unroll
    for (int i = 0; i < 32; ++i) byteMode |= (mw[i] > 1u);

    // Y column resident in 30 VGPRs (each Y element read from HBM once).
    float yr[NBASIS];
    const float* Yp = Y + (size_t)c * NBASIS * NX + n;
    #pragma unroll
    for (int b = 0; b < NBASIS; ++b) {
        yr[b] = Yp[(size_t)b * NX];
        asm volatile("" : "+v"(yr[b]));   // forbid remat/sink
    }

    const unsigned char* m8  = (const unsigned char*)maskT + n;
    const int*           m32 = (const int*)maskT + n;
    float* outp = out + (size_t)c * NF * NX + n;

    // Prefetch mask for f0 = 0.
    unsigned mcur[FT];
    #pragma unroll
    for (int j = 0; j < FT; ++j)
        mcur[j] = byteMode ? (unsigned)m8[(size_t)j * NX]
                           : (unsigned)m32[(size_t)j * NX];

    #pragma unroll 1
    for (int f0 = 0; f0 < NF; f0 += FT) {
        // Prefetch next iteration's mask (consumed after this FMA block).
        unsigned mnext[FT];
        if (f0 + FT < NF) {
            #pragma unroll
            for (int j = 0; j < FT; ++j)
                mnext[j] = byteMode ? (unsigned)m8[(size_t)(f0 + FT + j) * NX]
                                    : (unsigned)m32[(size_t)(f0 + FT + j) * NX];
        }

        float acc[FT];
        #pragma unroll
        for (int j = 0; j < FT; ++j) acc[j] = 0.0f;

        #pragma unroll
        for (int b = 0; b < NBASIS; ++b) {
            float y = yr[b];
            #pragma unroll
            for (int j = 0; j < FT; ++j)
                acc[j] = fmaf(y, VT[b * NF + f0 + j], acc[j]);  // vt uniform -> SGPR
        }

        #pragma unroll
        for (int j = 0; j < FT; ++j) {
            float o = (mcur[j] != 0u) ? acc[j] : 0.0f;
            __builtin_nontemporal_store(o, outp + (size_t)(f0 + j) * NX);
        }

        #pragma unroll
        for (int j = 0; j < FT; ++j) mcur[j] = mnext[j];
    }
}

extern "C" void kernel_launch(void* const* d_in, const int* in_sizes, int n_in,
                              void* d_out, int out_size, void* d_ws, size_t ws_size,
                              hipStream_t stream) {
    const float* x    = (const float*)d_in[0];   // (30,256,256,2) f32
    const float* csm  = (const float*)d_in[1];   // (8,256,256,2) f32
    const float* VT   = (const float*)d_in[2];   // (30,200) f32
    const void*  mask = d_in[3];                 // (200,131072) bool/int
    float* out = (float*)d_out;                  // (8,200,131072) f32
    float* A   = (float*)d_ws;                   // 240*256*256*2 f32 = 125.8 MB

    fft_rows_kernel<<<NIMG * 64, 256, 0, stream>>>(x, csm, A);
    fft_cols_kernel<<<NIMG * 16, 256, 0, stream>>>(A);
    project_mask_kernel<<<dim3(NX / 256, NCH), 256, 0, stream>>>(A, VT, mask, out);
}